// Round 3
// baseline (76.999 us; speedup 1.0000x reference)
//
#include <hip/hip_runtime.h>

// Sizes (fixed by the reference)
#define Bq 32
#define Gq 16
#define Oq 256
#define Nq 88
#define Tq 256

typedef short bf16x8 __attribute__((ext_vector_type(8)));   // 8 bf16 in 4 VGPRs
typedef float f32x4 __attribute__((ext_vector_type(4)));

static __device__ __forceinline__ short f2bf(float f) {
    return __builtin_bit_cast(short, (__bf16)f);  // RNE convert, bits as short
}

// Async global->LDS, 16B per lane. Dest = wave-uniform base + lane*16 (linear).
// Source is per-lane -> swizzle applied on the GLOBAL side (rule 21).
static __device__ __forceinline__ void gld_lds16(const float* src, float* lds_dst) {
    __builtin_amdgcn_global_load_lds(
        (const __attribute__((address_space(1))) void*)src,
        (__attribute__((address_space(3))) void*)lds_dst, 16, 0, 0);
}

// out[b,n,o] = sum_{g,t} x[b,n,t] * y[b,g] * w[g,o,n,t] * mask[o,t] + bias[o]
//
// Block = (n-PAIR, 16-wide o-tile): 8 waves (512 thr), each wave owns one
// K=32 t-window. Per g: stage w[g, o0:o0+16, n0:n0+2, :] = 16 x 2KB CONTIGUOUS
// runs (adjacent n rows are back-to-back in w) via global_load_lds, 2 instr
// per run -> half the device-wide stream count, 2x the sequential run length
// vs the 1-n version (attacks DRAM row-buffer efficiency, the measured 63%->
// target ~75% of peak). A-frags (x->bf16) built once for all g; y[b,g] applied
// per-g to the f32 MFMA partial. XOR swizzle chunk^=(o-row&7) on both sides.
__global__ __launch_bounds__(512, 4)
void mlm_mfma3(const float* __restrict__ x, const float* __restrict__ y,
               const float* __restrict__ w, const float* __restrict__ mask,
               const float* __restrict__ bias, float* __restrict__ out) {
    __shared__ float wbuf[2][8192];   // [buf][32 rows, i = o_r*2+nn][256 floats]
    __shared__ float y_lds[512];      // y[b][g] row-major

    const int unit = blockIdx.x;
    const int n0 = (unit >> 4) * 2;          // n-pair base, 0..86
    const int o0 = (unit & 15) << 4;         // o-tile base
    const int tid  = threadIdx.x;
    const int wv   = tid >> 6;        // 0..7 -> t-window [wv*32, wv*32+32)
    const int lane = tid & 63;
    const int lo = lane & 15;         // A row-slot / B col (o) / C col
    const int hi = lane >> 4;         // k-group 0..3
    const int sr = lo & 7;            // read-side swizzle key (o-row = lo)

    y_lds[tid] = y[tid];              // 512 elements, one per thread

    // A fragments (x -> bf16) and mask chunks: built once, live for all 16 g.
    // sigma: frag elem (hi,j): j<4 -> t = tA+j ; j>=4 -> t = tA+16+j-4
    const int tA = wv * 32 + hi * 4;
    const int tB = tA + 16;
    f32x4 mka = *(const f32x4*)(mask + (size_t)(o0 + lo) * Tq + tA);
    f32x4 mkb = *(const f32x4*)(mask + (size_t)(o0 + lo) * Tq + tB);
    bf16x8 afrag[2][2];               // [nn][b-half]
#pragma unroll
    for (int nn = 0; nn < 2; ++nn) {
        f32x4 xa0 = *(const f32x4*)(x + ((size_t)lo * Nq + n0 + nn) * Tq + tA);
        f32x4 xb0 = *(const f32x4*)(x + ((size_t)lo * Nq + n0 + nn) * Tq + tB);
        f32x4 xa1 = *(const f32x4*)(x + ((size_t)(lo + 16) * Nq + n0 + nn) * Tq + tA);
        f32x4 xb1 = *(const f32x4*)(x + ((size_t)(lo + 16) * Nq + n0 + nn) * Tq + tB);
#pragma unroll
        for (int j = 0; j < 4; ++j) {
            afrag[nn][0][j]     = f2bf(xa0[j]);
            afrag[nn][0][j + 4] = f2bf(xb0[j]);
            afrag[nn][1][j]     = f2bf(xa1[j]);
            afrag[nn][1][j + 4] = f2bf(xb1[j]);
        }
    }

    // staging sources: wave wv stages LDS rows i = wv*4+q, i = o_r*2 + nn
    const size_t GS = (size_t)Oq * Nq * Tq;   // g-stride in floats
    const float* wsrc[4];
#pragma unroll
    for (int q = 0; q < 4; ++q) {
        const int i = wv * 4 + q, r = i >> 1, nn = i & 1;
        wsrc[q] = w + ((size_t)(o0 + r) * Nq + n0 + nn) * Tq + ((lane ^ (r & 7)) << 2);
    }

    // stage g = 0 into buf 0
#pragma unroll
    for (int q = 0; q < 4; ++q)
        gld_lds16(wsrc[q], &wbuf[0][(wv * 4 + q) * 256]);
    asm volatile("s_waitcnt vmcnt(0)" ::: "memory");
    __syncthreads();

    f32x4 facc[2][2] = {};   // [nn][b-half], y-weighted f32 accumulators

    for (int g = 0; g < 16; ++g) {
        const int cb = g & 1;
        if (g < 15) {
#pragma unroll
            for (int q = 0; q < 4; ++q)
                gld_lds16(wsrc[q] + (size_t)(g + 1) * GS,
                          &wbuf[cb ^ 1][(wv * 4 + q) * 256]);
        }

        // y[b,g] for this lane's 8 C rows (shared across nn)
        float yv0[4], yv1[4];
#pragma unroll
        for (int i = 0; i < 4; ++i) {
            yv0[i] = y_lds[(hi * 4 + i) * Gq + g];
            yv1[i] = y_lds[(16 + hi * 4 + i) * Gq + g];
        }

        const int c0 = wv * 8 + hi;   // logical 16B-chunk of wa within row
#pragma unroll
        for (int nn = 0; nn < 2; ++nn) {
            f32x4 wa4 = *(const f32x4*)&wbuf[cb][(lo * 2 + nn) * 256 + ((c0 ^ sr) << 2)];
            f32x4 wb4 = *(const f32x4*)&wbuf[cb][(lo * 2 + nn) * 256 + (((c0 + 4) ^ sr) << 2)];
            bf16x8 bfr;
#pragma unroll
            for (int j = 0; j < 4; ++j) {
                bfr[j]     = f2bf(wa4[j] * mka[j]);
                bfr[j + 4] = f2bf(wb4[j] * mkb[j]);
            }
            f32x4 z = {0.f, 0.f, 0.f, 0.f};
            f32x4 a0 = __builtin_amdgcn_mfma_f32_16x16x32_bf16(afrag[nn][0], bfr, z, 0, 0, 0);
            f32x4 a1 = __builtin_amdgcn_mfma_f32_16x16x32_bf16(afrag[nn][1], bfr, z, 0, 0, 0);
#pragma unroll
            for (int i = 0; i < 4; ++i) {
                facc[nn][0][i] += yv0[i] * a0[i];
                facc[nn][1][i] += yv1[i] * a1[i];
            }
        }

        asm volatile("s_waitcnt vmcnt(0)" ::: "memory");
        __syncthreads();
    }

    // cross-wave (t-split) reduction; overlay red on wbuf[0] (g=15 read buf 1)
    float (*red)[2][32][16] = (float (*)[2][32][16]) & wbuf[0][0];  // 32 KB
#pragma unroll
    for (int i = 0; i < 4; ++i) {
#pragma unroll
        for (int nn = 0; nn < 2; ++nn) {
            red[wv][nn][hi * 4 + i][lo]      = facc[nn][0][i];
            red[wv][nn][16 + hi * 4 + i][lo] = facc[nn][1][i];
        }
    }
    __syncthreads();

    // 1024 outputs (2 n x 32 b x 16 o), 512 threads -> 2 each; sum 8 partials
#pragma unroll
    for (int s = 0; s < 2; ++s) {
        const int idx = tid + s * 512;
        const int nn  = idx >> 9;
        const int b   = (idx >> 4) & 31;
        const int oo  = idx & 15;
        float v = bias[o0 + oo];
#pragma unroll
        for (int p = 0; p < 8; ++p) v += red[p][nn][b][oo];
        out[((size_t)b * Nq + n0 + nn) * Oq + o0 + oo] = v;
    }
}

extern "C" void kernel_launch(void* const* d_in, const int* in_sizes, int n_in,
                              void* d_out, int out_size, void* d_ws, size_t ws_size,
                              hipStream_t stream) {
    const float* x    = (const float*)d_in[0];
    const float* y    = (const float*)d_in[1];
    const float* w    = (const float*)d_in[2];
    const float* mask = (const float*)d_in[3];
    const float* bias = (const float*)d_in[4];
    float* out = (float*)d_out;

    dim3 grid((Nq / 2) * (Oq / 16));  // 44 n-pairs * 16 o-tiles = 704 blocks
    dim3 block(512);
    hipLaunchKernelGGL(mlm_mfma3, grid, block, 0, stream, x, y, w, mask, bias, out);
}